// Round 10
// baseline (274.599 us; speedup 1.0000x reference)
//
#include <hip/hip_runtime.h>
#include <cstddef>
#include <cstdint>

#define Tn 52
#define Fn 64
#define Hn 32
#define Bn 8192
#define XHAT_ELEMS (Bn * Tn * Fn)   // fp32 elems of x_hat; xs1 bf16 plane fits in half
#define L2E 1.44269504088896340736f

typedef __attribute__((ext_vector_type(8))) short bf8v;   // 8 bf16 (4 VGPRs)
typedef __attribute__((ext_vector_type(4))) float f4v;    // 4 fp32 accum

__device__ __forceinline__ f4v mfma_bf16(bf8v a, bf8v b, f4v c) {
    return __builtin_amdgcn_mfma_f32_16x16x32_bf16(a, b, c, 0, 0, 0);
}

// RNE round to bf16
__device__ __forceinline__ unsigned short rne_bf16(float v) {
    unsigned b = __float_as_uint(v);
    unsigned r = ((b >> 16) & 1u) + 0x7FFFu;
    return (unsigned short)((b + r) >> 16);
}

__device__ __forceinline__ bf8v rne8(float4 a, float4 b) {
    float v[8] = {a.x, a.y, a.z, a.w, b.x, b.y, b.z, b.w};
    bf8v r;
#pragma unroll
    for (int j = 0; j < 8; ++j) r[j] = (short)rne_bf16(v[j]);
    return r;
}

// barrier WITHOUT vmcnt drain: LDS ops are compiler-visible, so
// lgkmcnt(0)+s_barrier is sufficient; global prefetch/stores stay in flight.
__device__ __forceinline__ void lds_barrier() {
    asm volatile("s_waitcnt lgkmcnt(0)" ::: "memory");
    __builtin_amdgcn_s_barrier();
}

// Gates pre-scaled by log2e (g-gate by 2*log2e). One rcp for c2, one for h.
__device__ __forceinline__ float lstm_one(float aI, float aF, float aG, float aO, float& cst) {
    float ei = exp2f(fminf(40.f, -aI));
    float ef = exp2f(fminf(40.f, -aF));
    float eg = exp2f(fminf(40.f, -aG));
    float eo = exp2f(fminf(40.f, -aO));
    float p   = (1.f + ei) * (1.f + eg);
    float num = cst * p + (1.f - eg) * (1.f + ef);
    float den = (1.f + ef) * p;
    float c2  = num * __builtin_amdgcn_rcpf(den);
    cst = c2;
    float e2 = exp2f(fminf(40.f, -2.f * L2E * c2));
    return (1.f - e2) * __builtin_amdgcn_rcpf((1.f + eo) * (1.f + e2));
}

// pin the 12 weight fragments live across the loop (defeats remat/reload)
#define PINW(W)                                                               \
    asm volatile("" : "+v"(W[0][0]), "+v"(W[0][1]), "+v"(W[0][2]),            \
                      "+v"(W[1][0]), "+v"(W[1][1]), "+v"(W[1][2]));           \
    asm volatile("" : "+v"(W[2][0]), "+v"(W[2][1]), "+v"(W[2][2]),            \
                      "+v"(W[3][0]), "+v"(W[3][1]), "+v"(W[3][2]));

// ---------------------------------------------------------------------------
// Prep: weights -> fragment-ordered RNE bf16, pre-scaled by log2e
// (g-gate rows by 2*log2e). [grp][cell(4)][nt(8)][ki(3)][lane(64)][j(8)]
//   gate = nt*16 + (lane&15); k = ki*32 + (lane>>4)*8 + j
// ---------------------------------------------------------------------------
__global__ void prep_kernel(const float* __restrict__ eWih, const float* __restrict__ eWhh,
                            const float* __restrict__ dWih, const float* __restrict__ dWhh,
                            unsigned short* __restrict__ ws)
{
    int fid = blockIdx.x * 256 + threadIdx.x;
    if (fid >= 12288) return;
    int lane = fid & 63;
    int ki   = (fid >> 6) % 3;
    int nt   = (fid / 192) & 7;
    int cell = (fid / 1536) & 3;
    int grp  = fid / 6144;
    const float* Wih = grp ? dWih : eWih;
    const float* Whh = grp ? dWhh : eWhh;
    int gate = nt * 16 + (lane & 15);
    float scale = ((gate >> 5) == 2) ? 2.f * L2E : L2E;
    int k0 = ki * 32 + (lane >> 4) * 8;
    size_t base = (size_t)grp * 98304 + (size_t)cell * 12288 + nt * 1536 + ki * 512 + lane * 8;
#pragma unroll
    for (int j = 0; j < 8; ++j) {
        int k = k0 + j;
        float v = (k < 64) ? Wih[(size_t)cell * 8192 + gate * 64 + k]
                           : Whh[(size_t)cell * 4096 + gate * 32 + (k - 64)];
        ws[base + j] = rne_bf16(v * scale);
    }
}

// ---------------------------------------------------------------------------
// Encoder layer (R8 structure): block = 256 thr (4 waves = dir x q-half),
// 16 rows, grid 512 -> 2 blocks/CU. x-part of t+1 hoisted pre-barrier.
// Pointer-increment addressing for x prefetch and xs1 stores.
// ---------------------------------------------------------------------------
template<int IS_L0>
__global__ __launch_bounds__(256, 2)
void enc_kernel(const float* __restrict__ X, const unsigned short* __restrict__ Xh,
                const float* __restrict__ h0, const float* __restrict__ c0,
                const unsigned short* __restrict__ Whi, const float* __restrict__ bias,
                int layer, unsigned short* __restrict__ outh, float* __restrict__ z)
{
    __shared__ __align__(16) unsigned short Hsh[2][2][16][40];   // [dir][parity][row][unit]
    const int tid = threadIdx.x, w = tid >> 6, lane = tid & 63;
    const int d = w >> 1, q = w & 1;
    const int a = lane & 15, kb = lane >> 4;
    const int u = q * 16 + a;
    const int row0 = blockIdx.x * 16;
    const int ci = 2 * layer + d;

    bf8v WH[4][3];   // 12 frags = 48 VGPR, pinned
#pragma unroll
    for (int g = 0; g < 4; ++g)
#pragma unroll
        for (int ki = 0; ki < 3; ++ki)
            WH[g][ki] = *(const bf8v*)(Whi + (size_t)ci * 12288 + (2 * g + q) * 1536
                                       + ki * 512 + lane * 8);
    f4v bC[4];       // bias splat as MFMA C-operand
#pragma unroll
    for (int g = 0; g < 4; ++g) {
        float bv = bias[ci * 128 + g * 32 + u] * ((g == 2) ? 2.f * L2E : L2E);
        bC[g] = (f4v){bv, bv, bv, bv};
    }
    float cst[4], hfin[4];
#pragma unroll
    for (int j = 0; j < 4; ++j)
        cst[j] = c0[((size_t)ci * Bn + row0 + 4 * kb + j) * Hn + u];

    {   // h0 -> parity 1: 2 dirs x 16 rows x 32 units / 256 thr = 4 each
        int dd = tid >> 7, rr = (tid >> 3) & 15, u4 = (tid & 7) * 4;
        const float* src = h0 + ((size_t)(2 * layer + dd) * Bn + row0 + rr) * Hn + u4;
#pragma unroll
        for (int e = 0; e < 4; ++e)
            Hsh[dd][1][rr][u4 + e] = rne_bf16(src[e]);
    }
    __syncthreads();

    const int grow = row0 + a;           // this lane's A-fragment row
    const int dstep = d ? -1 : 1;
    const float* xpf = nullptr; const unsigned short* xph = nullptr;
    float4 p0, p1, p2, p3; bf8v ph0, ph1;
    f4v acc[4];
    {   // t = 0: x-part into acc; load t = 1 into p; xpf/xph -> t = 2
        int tt0 = d ? (Tn - 1) : 0;
        bf8v xf0, xf1;
        if (IS_L0) {
            const float* sp = X + ((size_t)grow * Tn + tt0) * Fn + kb * 8;
            xf0 = rne8(*(const float4*)sp, *(const float4*)(sp + 4));
            xf1 = rne8(*(const float4*)(sp + 32), *(const float4*)(sp + 36));
        } else {
            const unsigned short* sp = Xh + ((size_t)tt0 * Bn + grow) * Fn + kb * 8;
            xf0 = *(const bf8v*)sp;
            xf1 = *(const bf8v*)(sp + 32);
        }
#pragma unroll
        for (int g = 0; g < 4; ++g)
            acc[g] = mfma_bf16(xf1, WH[g][1], mfma_bf16(xf0, WH[g][0], bC[g]));
        int tt1 = tt0 + dstep;
        if (IS_L0) {
            const float* sp = X + ((size_t)grow * Tn + tt1) * Fn + kb * 8;
            p0 = *(const float4*)sp;        p1 = *(const float4*)(sp + 4);
            p2 = *(const float4*)(sp + 32); p3 = *(const float4*)(sp + 36);
            xpf = sp + (ptrdiff_t)dstep * Fn;
        } else {
            const unsigned short* sp = Xh + ((size_t)tt1 * Bn + grow) * Fn + kb * 8;
            ph0 = *(const bf8v*)sp;
            ph1 = *(const bf8v*)(sp + 32);
            xph = sp + (ptrdiff_t)dstep * Bn * Fn;
        }
    }
    unsigned short* op[4];
    const ptrdiff_t ostep = (ptrdiff_t)dstep * Bn * Fn;
    if (IS_L0) {
        int tp0 = d ? (Tn - 1) : 0;
#pragma unroll
        for (int j = 0; j < 4; ++j)
            op[j] = outh + ((size_t)tp0 * Bn + row0 + 4 * kb + j) * Fn + d * 32 + u;
    }

    for (int t = 0; t < Tn; ++t) {
        PINW(WH);
        // post-barrier critical path: h-read -> 4 MFMA -> lstm -> write
        bf8v hh = *(const bf8v*)&Hsh[d][(t & 1) ^ 1][a][kb * 8];
#pragma unroll
        for (int g = 0; g < 4; ++g) acc[g] = mfma_bf16(hh, WH[g][2], acc[g]);
#pragma unroll
        for (int j = 0; j < 4; ++j) {
            float hv = lstm_one(acc[0][j], acc[1][j], acc[2][j], acc[3][j], cst[j]);
            hfin[j] = hv;
            unsigned short hp = rne_bf16(hv);
            Hsh[d][t & 1][4 * kb + j][u] = hp;
            if (IS_L0) { *op[j] = hp; op[j] += ostep; }
        }
        // pre-barrier: x-part of t+1 + prefetch t+2 (independent of h)
        {
            bf8v xf0, xf1;
            if (IS_L0) { xf0 = rne8(p0, p1); xf1 = rne8(p2, p3); }
            else       { xf0 = ph0; xf1 = ph1; }
#pragma unroll
            for (int g = 0; g < 4; ++g)
                acc[g] = mfma_bf16(xf1, WH[g][1], mfma_bf16(xf0, WH[g][0], bC[g]));
            if (IS_L0) {
                p0 = *(const float4*)xpf;        p1 = *(const float4*)(xpf + 4);
                p2 = *(const float4*)(xpf + 32); p3 = *(const float4*)(xpf + 36);
                if (t + 3 < Tn) xpf += (ptrdiff_t)dstep * Fn;
            } else {
                ph0 = *(const bf8v*)xph;
                ph1 = *(const bf8v*)(xph + 32);
                if (t + 3 < Tn) xph += (ptrdiff_t)dstep * Bn * Fn;
            }
        }
        lds_barrier();
    }
#pragma unroll
    for (int j = 0; j < 4; ++j) {
        size_t zr = (size_t)(row0 + 4 * kb + j) * 256;
        z[zr + ci * 32 + u]       = hfin[j];
        z[zr + 128 + ci * 32 + u] = cst[j];
    }
}

// ---------------------------------------------------------------------------
// Decoder: block = 512 thr (8 waves: P x cell x q-half), 32 rows = 2 groups,
// grid 256. Slot pipeline: A (cells 0,1) on group g, B (cells 2,3) on g^1.
// h-part of next slot hoisted pre-barrier; x2 unroll (static parity);
// setprio around MFMA clusters; pointer-increment xhat addressing.
// ---------------------------------------------------------------------------
__global__ __launch_bounds__(512, 2)
void dec_kernel(const unsigned short* __restrict__ Whi, const float* __restrict__ bias,
                const float* __restrict__ z, float* __restrict__ xhat)
{
    __shared__ __align__(16) unsigned short Ysh[2][2][16][72];      // [grp][par][row][feat]
    __shared__ __align__(16) unsigned short Msh[2][16][72];         // [grp][row][feat]
    __shared__ __align__(16) unsigned short Hsh[4][2][2][16][40];   // [cell][grp][par][row][unit]

    const int tid = threadIdx.x, w = tid >> 6, lane = tid & 63;
    const int P = w >> 2, cl = (w >> 1) & 1, q = w & 1;
    const int cell = P * 2 + cl;
    const int a = lane & 15, kb = lane >> 4, u = q * 16 + a;
    const int row0 = blockIdx.x * 32;

    bf8v WH[4][3];   // 12 frags = 48 VGPR, pinned
#pragma unroll
    for (int g = 0; g < 4; ++g)
#pragma unroll
        for (int ki = 0; ki < 3; ++ki)
            WH[g][ki] = *(const bf8v*)(Whi + (size_t)cell * 12288 + (2 * g + q) * 1536
                                       + ki * 512 + lane * 8);
    f4v bC[4];
#pragma unroll
    for (int g = 0; g < 4; ++g) {
        float bv = bias[cell * 128 + g * 32 + u] * ((g == 2) ? 2.f * L2E : L2E);
        bC[g] = (f4v){bv, bv, bv, bv};
    }

    float cst[2][4];   // [group][j]
#pragma unroll
    for (int G = 0; G < 2; ++G)
#pragma unroll
        for (int j = 0; j < 4; ++j)
            cst[G][j] = z[(size_t)(row0 + G * 16 + 4 * kb + j) * 256 + 128 + cell * 32 + u];

    // moving xhat pointers: [group][j], advanced by Fn after each store
    float* xp_[2][4];
#pragma unroll
    for (int G = 0; G < 2; ++G)
#pragma unroll
        for (int j = 0; j < 4; ++j)
            xp_[G][j] = xhat + (size_t)(row0 + G * 16 + 4 * kb + j) * Tn * Fn + cl * 32 + u;

    {   // h-init -> parity-1: 4 cells x 32 rows x 32 units / 512 thr = 8 each
        int ct = tid >> 7, rem = tid & 127, rr = rem >> 2, u8 = (rem & 3) * 8;
        const float* src = z + (size_t)(row0 + rr) * 256 + ct * 32 + u8;
#pragma unroll
        for (int e = 0; e < 8; ++e)
            Hsh[ct][rr >> 4][1][rr & 15][u8 + e] = rne_bf16(src[e]);
    }
    __syncthreads();

    f4v accp[4];
    // h-part precompute for the wave's NEXT work item (wave-private h);
    // bias enters as the MFMA C-operand.
    auto hpart = [&](int G, int rpar) {
        bf8v hh = *(const bf8v*)&Hsh[cell][G][rpar][a][kb * 8];
        __builtin_amdgcn_s_setprio(1);
#pragma unroll
        for (int g = 0; g < 4; ++g) accp[g] = mfma_bf16(hh, WH[g][2], bC[g]);
        __builtin_amdgcn_s_setprio(0);
    };
    // post-barrier finish: V-read -> 8 MFMA -> lstm -> writes. par == t&1.
    auto finish = [&](int G, int par, bool isA, bool hasV) {
        if (hasV) {
            const unsigned short (*Vh)[72] = isA ? Ysh[G][par ^ 1] : Msh[G];
            bf8v vh0 = *(const bf8v*)&Vh[a][kb * 8];
            bf8v vh1 = *(const bf8v*)&Vh[a][32 + kb * 8];
            __builtin_amdgcn_s_setprio(1);
#pragma unroll
            for (int g = 0; g < 4; ++g) {
                accp[g] = mfma_bf16(vh0, WH[g][0], accp[g]);
                accp[g] = mfma_bf16(vh1, WH[g][1], accp[g]);
            }
            __builtin_amdgcn_s_setprio(0);
        }
#pragma unroll
        for (int j = 0; j < 4; ++j) {
            float hv = lstm_one(accp[0][j], accp[1][j], accp[2][j], accp[3][j], cst[G][j]);
            unsigned short hp = rne_bf16(hv);
            int r = 4 * kb + j;
            Hsh[cell][G][par][r][u] = hp;
            if (isA) {
                Msh[G][r][cl * 32 + u] = hp;
            } else {
                Ysh[G][par][r][cl * 32 + u] = hp;
                *xp_[G][j] = hv;
                xp_[G][j] += Fn;
            }
        }
    };

    hpart(0, 1);   // prologue: both A and B start on (G0, t=0)
    for (int it = 0; it < Tn / 2; ++it) {
        const bool nz = (it > 0);
        PINW(WH);
        // ---- t0 = 2it (par 0) ---- slot even: A(G0,t0), B(G1,t0-1)
        if (P == 0) { finish(0, 0, true, nz);            hpart(1, 1); }
        else        { if (nz) finish(1, 1, false, true); hpart(0, 1); }
        lds_barrier();
        //                            slot odd: A(G1,t0), B(G0,t0)
        if (P == 0) { finish(1, 0, true, nz);            hpart(0, 0); }
        else        { finish(0, 0, false, true);         hpart(1, 1); }
        lds_barrier();
        PINW(WH);
        // ---- t1 = 2it+1 (par 1) -- slot even: A(G0,t1), B(G1,t0)
        if (P == 0) { finish(0, 1, true, true);          hpart(1, 0); }
        else        { finish(1, 0, false, true);         hpart(0, 0); }
        lds_barrier();
        //                            slot odd: A(G1,t1), B(G0,t1)
        if (P == 0) { finish(1, 1, true, true);          hpart(0, 1); }
        else        { finish(0, 1, false, true);         hpart(1, 0); }
        lds_barrier();
    }
    if (P == 1) finish(1, 1, false, true);   // epilogue: G1 last step (t = Tn-1)
}

extern "C" void kernel_launch(void* const* d_in, const int* in_sizes, int n_in,
                              void* d_out, int out_size, void* d_ws, size_t ws_size,
                              hipStream_t stream) {
    const float* x    = (const float*)d_in[0];
    const float* h0   = (const float*)d_in[1];
    const float* c0   = (const float*)d_in[2];
    const float* eWih = (const float*)d_in[3];
    const float* eWhh = (const float*)d_in[4];
    const float* eb   = (const float*)d_in[5];
    const float* dWih = (const float*)d_in[6];
    const float* dWhh = (const float*)d_in[7];
    const float* db   = (const float*)d_in[8];

    float* out = (float*)d_out;
    unsigned short* xs1h = (unsigned short*)d_out;          // [T,B,64] bf16 plane
    float* zb = out + (size_t)XHAT_ELEMS;                   // [B,256] latent
    unsigned short* wsb = (unsigned short*)d_ws;            // weight fragments

    hipLaunchKernelGGL(prep_kernel, dim3(48), dim3(256), 0, stream,
                       eWih, eWhh, dWih, dWhh, wsb);
    // encoder layer 0: x -> xs1 plane + z slots 0,1
    hipLaunchKernelGGL((enc_kernel<1>), dim3(Bn / 16), dim3(256), 0, stream,
                       x, (const unsigned short*)nullptr,
                       h0, c0, wsb, eb, 0, xs1h, zb);
    // encoder layer 1: xs1 plane -> z slots 2,3
    hipLaunchKernelGGL((enc_kernel<0>), dim3(Bn / 16), dim3(256), 0, stream,
                       (const float*)nullptr, xs1h,
                       h0, c0, wsb, eb, 1, (unsigned short*)nullptr, zb);
    // decoder: z -> x_hat (overwrites xs1 region)
    hipLaunchKernelGGL(dec_kernel, dim3(Bn / 32), dim3(512), 0, stream,
                       wsb + 98304, db, zb, out);
}

// Round 11
// 264.749 us; speedup vs baseline: 1.0372x; 1.0372x over previous
//
#include <hip/hip_runtime.h>
#include <cstddef>
#include <cstdint>

#define Tn 52
#define Fn 64
#define Hn 32
#define Bn 8192
#define XHAT_ELEMS (Bn * Tn * Fn)   // fp32 elems of x_hat; xs1 bf16 plane fits in half
#define L2E 1.44269504088896340736f

typedef __attribute__((ext_vector_type(8))) short bf8v;   // 8 bf16 (4 VGPRs)
typedef __attribute__((ext_vector_type(4))) float f4v;    // 4 fp32 accum

__device__ __forceinline__ f4v mfma_bf16(bf8v a, bf8v b, f4v c) {
    return __builtin_amdgcn_mfma_f32_16x16x32_bf16(a, b, c, 0, 0, 0);
}

// RNE round to bf16
__device__ __forceinline__ unsigned short rne_bf16(float v) {
    unsigned b = __float_as_uint(v);
    unsigned r = ((b >> 16) & 1u) + 0x7FFFu;
    return (unsigned short)((b + r) >> 16);
}

__device__ __forceinline__ bf8v rne8(float4 a, float4 b) {
    float v[8] = {a.x, a.y, a.z, a.w, b.x, b.y, b.z, b.w};
    bf8v r;
#pragma unroll
    for (int j = 0; j < 8; ++j) r[j] = (short)rne_bf16(v[j]);
    return r;
}

// barrier variant used by the best-measured ENCODER (R7 proposal): sched pins
// keep the compiler from reordering across the barrier.
__device__ __forceinline__ void lds_barrier_pinned() {
    __builtin_amdgcn_sched_barrier(0);
    asm volatile("s_waitcnt lgkmcnt(0)" ::: "memory");
    __builtin_amdgcn_s_barrier();
    __builtin_amdgcn_sched_barrier(0);
}

// barrier variant used by the best-measured DECODER (R8 proposal): relaxed,
// scheduler may hoist independent register work across.
__device__ __forceinline__ void lds_barrier_relaxed() {
    asm volatile("s_waitcnt lgkmcnt(0)" ::: "memory");
    __builtin_amdgcn_s_barrier();
}

// Gates pre-scaled by log2e (g-gate by 2*log2e). One rcp for c2, one for h.
__device__ __forceinline__ float lstm_one(float aI, float aF, float aG, float aO, float& cst) {
    float ei = exp2f(fminf(40.f, -aI));
    float ef = exp2f(fminf(40.f, -aF));
    float eg = exp2f(fminf(40.f, -aG));
    float eo = exp2f(fminf(40.f, -aO));
    float p   = (1.f + ei) * (1.f + eg);
    float num = cst * p + (1.f - eg) * (1.f + ef);
    float den = (1.f + ef) * p;
    float c2  = num * __builtin_amdgcn_rcpf(den);
    cst = c2;
    float e2 = exp2f(fminf(40.f, -2.f * L2E * c2));
    return (1.f - e2) * __builtin_amdgcn_rcpf((1.f + eo) * (1.f + e2));
}

// pin the 12 weight fragments live across the loop (defeats remat/reload)
#define PINW(W)                                                               \
    asm volatile("" : "+v"(W[0][0]), "+v"(W[0][1]), "+v"(W[0][2]),            \
                      "+v"(W[1][0]), "+v"(W[1][1]), "+v"(W[1][2]));           \
    asm volatile("" : "+v"(W[2][0]), "+v"(W[2][1]), "+v"(W[2][2]),            \
                      "+v"(W[3][0]), "+v"(W[3][1]), "+v"(W[3][2]));

// ---------------------------------------------------------------------------
// Prep: weights -> fragment-ordered RNE bf16, pre-scaled by log2e
// (g-gate rows by 2*log2e). [grp][cell(4)][nt(8)][ki(3)][lane(64)][j(8)]
//   gate = nt*16 + (lane&15); k = ki*32 + (lane>>4)*8 + j
// ---------------------------------------------------------------------------
__global__ void prep_kernel(const float* __restrict__ eWih, const float* __restrict__ eWhh,
                            const float* __restrict__ dWih, const float* __restrict__ dWhh,
                            unsigned short* __restrict__ ws)
{
    int fid = blockIdx.x * 256 + threadIdx.x;
    if (fid >= 12288) return;
    int lane = fid & 63;
    int ki   = (fid >> 6) % 3;
    int nt   = (fid / 192) & 7;
    int cell = (fid / 1536) & 3;
    int grp  = fid / 6144;
    const float* Wih = grp ? dWih : eWih;
    const float* Whh = grp ? dWhh : eWhh;
    int gate = nt * 16 + (lane & 15);
    float scale = ((gate >> 5) == 2) ? 2.f * L2E : L2E;
    int k0 = ki * 32 + (lane >> 4) * 8;
    size_t base = (size_t)grp * 98304 + (size_t)cell * 12288 + nt * 1536 + ki * 512 + lane * 8;
#pragma unroll
    for (int j = 0; j < 8; ++j) {
        int k = k0 + j;
        float v = (k < 64) ? Wih[(size_t)cell * 8192 + gate * 64 + k]
                           : Whh[(size_t)cell * 4096 + gate * 32 + (k - 64)];
        ws[base + j] = rne_bf16(v * scale);
    }
}

// ---------------------------------------------------------------------------
// Encoder layer (verbatim R7-proposal structure, the best-measured ~125 us
// pair): block = 256 thr (4 waves = dir x q-half), 16 rows, grid 512.
// Single-bf16 activations; x-part MFMAs of step t+1 hoisted BEFORE the
// barrier (post-barrier path = h-read -> 4 MFMA -> lstm -> write).
// ---------------------------------------------------------------------------
template<int IS_L0>
__global__ __launch_bounds__(256, 2)
void enc_kernel(const float* __restrict__ X, const unsigned short* __restrict__ Xh,
                const float* __restrict__ h0, const float* __restrict__ c0,
                const unsigned short* __restrict__ Whi, const float* __restrict__ bias,
                int layer, unsigned short* __restrict__ outh, float* __restrict__ z)
{
    __shared__ __align__(16) unsigned short Hsh[2][2][16][40];   // [dir][parity][row][unit]
    const int tid = threadIdx.x, w = tid >> 6, lane = tid & 63;
    const int d = w >> 1, q = w & 1;
    const int a = lane & 15, kb = lane >> 4;
    const int u = q * 16 + a;
    const int row0 = blockIdx.x * 16;
    const int ci = 2 * layer + d;

    bf8v WH[4][3];   // 12 frags = 48 VGPR, pinned
#pragma unroll
    for (int g = 0; g < 4; ++g)
#pragma unroll
        for (int ki = 0; ki < 3; ++ki)
            WH[g][ki] = *(const bf8v*)(Whi + (size_t)ci * 12288 + (2 * g + q) * 1536
                                       + ki * 512 + lane * 8);
    float bj[4];
#pragma unroll
    for (int g = 0; g < 4; ++g)
        bj[g] = bias[ci * 128 + g * 32 + u] * ((g == 2) ? 2.f * L2E : L2E);
    float cst[4], hfin[4];
#pragma unroll
    for (int j = 0; j < 4; ++j)
        cst[j] = c0[((size_t)ci * Bn + row0 + 4 * kb + j) * Hn + u];

    {   // h0 -> parity 1: 2 dirs x 16 rows x 32 units / 256 thr = 4 each
        int dd = tid >> 7, rr = (tid >> 3) & 15, u4 = (tid & 7) * 4;
        const float* src = h0 + ((size_t)(2 * layer + dd) * Bn + row0 + rr) * Hn + u4;
#pragma unroll
        for (int e = 0; e < 4; ++e)
            Hsh[dd][1][rr][u4 + e] = rne_bf16(src[e]);
    }
    __syncthreads();

    const int grow = row0 + a;   // this lane's A-fragment row
    float4 p0, p1, p2, p3; bf8v ph0, ph1;
    f4v acc[4];
    {   // t = 0: load x, build acc = bias + x-part; prefetch t = 1
        int tt = d ? (Tn - 1) : 0;
        bf8v xf0, xf1;
        if (IS_L0) {
            const float* sp = X + ((size_t)grow * Tn + tt) * Fn;
            xf0 = rne8(*(const float4*)(sp + kb * 8), *(const float4*)(sp + kb * 8 + 4));
            xf1 = rne8(*(const float4*)(sp + 32 + kb * 8), *(const float4*)(sp + 32 + kb * 8 + 4));
        } else {
            size_t so = ((size_t)tt * Bn + grow) * Fn + kb * 8;
            xf0 = *(const bf8v*)(Xh + so);
            xf1 = *(const bf8v*)(Xh + so + 32);
        }
#pragma unroll
        for (int g = 0; g < 4; ++g) {
            acc[g] = (f4v){bj[g], bj[g], bj[g], bj[g]};
            acc[g] = mfma_bf16(xf0, WH[g][0], acc[g]);
            acc[g] = mfma_bf16(xf1, WH[g][1], acc[g]);
        }
        int tt1 = d ? (Tn - 2) : 1;
        if (IS_L0) {
            const float* sp = X + ((size_t)grow * Tn + tt1) * Fn;
            p0 = *(const float4*)(sp + kb * 8);      p1 = *(const float4*)(sp + kb * 8 + 4);
            p2 = *(const float4*)(sp + 32 + kb * 8); p3 = *(const float4*)(sp + 32 + kb * 8 + 4);
        } else {
            size_t so = ((size_t)tt1 * Bn + grow) * Fn + kb * 8;
            ph0 = *(const bf8v*)(Xh + so);
            ph1 = *(const bf8v*)(Xh + so + 32);
        }
    }

    for (int t = 0; t < Tn; ++t) {
        PINW(WH);
        // post-barrier critical path: h-read -> 4 MFMA -> lstm -> write
        bf8v hh = *(const bf8v*)&Hsh[d][(t & 1) ^ 1][a][kb * 8];
#pragma unroll
        for (int g = 0; g < 4; ++g) acc[g] = mfma_bf16(hh, WH[g][2], acc[g]);
        int tp = d ? (Tn - 1 - t) : t;
#pragma unroll
        for (int j = 0; j < 4; ++j) {
            float hv = lstm_one(acc[0][j], acc[1][j], acc[2][j], acc[3][j], cst[j]);
            hfin[j] = hv;
            unsigned short hp = rne_bf16(hv);
            Hsh[d][t & 1][4 * kb + j][u] = hp;
            if (IS_L0)
                outh[((size_t)tp * Bn + row0 + 4 * kb + j) * Fn + d * 32 + u] = hp;
        }
        // pre-barrier: x-part of t+1 + prefetch t+2 (independent of h)
        {
            bf8v xf0, xf1;
            if (IS_L0) { xf0 = rne8(p0, p1); xf1 = rne8(p2, p3); }
            else       { xf0 = ph0; xf1 = ph1; }
#pragma unroll
            for (int g = 0; g < 4; ++g) {
                f4v t0 = (f4v){bj[g], bj[g], bj[g], bj[g]};
                t0 = mfma_bf16(xf0, WH[g][0], t0);
                acc[g] = mfma_bf16(xf1, WH[g][1], t0);
            }
            int ts = (t + 2 < Tn) ? t + 2 : Tn - 1;
            int tt = d ? (Tn - 1 - ts) : ts;
            if (IS_L0) {
                const float* sp = X + ((size_t)grow * Tn + tt) * Fn;
                p0 = *(const float4*)(sp + kb * 8);      p1 = *(const float4*)(sp + kb * 8 + 4);
                p2 = *(const float4*)(sp + 32 + kb * 8); p3 = *(const float4*)(sp + 32 + kb * 8 + 4);
            } else {
                size_t so = ((size_t)tt * Bn + grow) * Fn + kb * 8;
                ph0 = *(const bf8v*)(Xh + so);
                ph1 = *(const bf8v*)(Xh + so + 32);
            }
        }
        lds_barrier_pinned();
    }
#pragma unroll
    for (int j = 0; j < 4; ++j) {
        size_t zr = (size_t)(row0 + 4 * kb + j) * 256;
        z[zr + ci * 32 + u]       = hfin[j];
        z[zr + 128 + ci * 32 + u] = cst[j];
    }
}

// ---------------------------------------------------------------------------
// Decoder (verbatim R8-proposal structure, the best-measured 138.6 us):
// block = 512 thr (8 waves: P x cell x q-half), 32 rows = 2 groups, grid 256.
// Slot pipeline: A (cells 0,1) on group g, B (cells 2,3) on g^1.
// h-part of next slot hoisted pre-barrier; x2 unroll (static parity);
// setprio(1) around MFMA clusters (A/B waves are role-split).
// ---------------------------------------------------------------------------
__global__ __launch_bounds__(512, 2)
void dec_kernel(const unsigned short* __restrict__ Whi, const float* __restrict__ bias,
                const float* __restrict__ z, float* __restrict__ xhat)
{
    __shared__ __align__(16) unsigned short Ysh[2][2][16][72];      // [grp][par][row][feat]
    __shared__ __align__(16) unsigned short Msh[2][16][72];         // [grp][row][feat]
    __shared__ __align__(16) unsigned short Hsh[4][2][2][16][40];   // [cell][grp][par][row][unit]

    const int tid = threadIdx.x, w = tid >> 6, lane = tid & 63;
    const int P = w >> 2, cl = (w >> 1) & 1, q = w & 1;
    const int cell = P * 2 + cl;
    const int a = lane & 15, kb = lane >> 4, u = q * 16 + a;
    const int row0 = blockIdx.x * 32;

    bf8v WH[4][3];   // 12 frags = 48 VGPR, pinned
#pragma unroll
    for (int g = 0; g < 4; ++g)
#pragma unroll
        for (int ki = 0; ki < 3; ++ki)
            WH[g][ki] = *(const bf8v*)(Whi + (size_t)cell * 12288 + (2 * g + q) * 1536
                                       + ki * 512 + lane * 8);
    f4v bC[4];
#pragma unroll
    for (int g = 0; g < 4; ++g) {
        float bv = bias[cell * 128 + g * 32 + u] * ((g == 2) ? 2.f * L2E : L2E);
        bC[g] = (f4v){bv, bv, bv, bv};
    }

    float cst[2][4];   // [group][j]
#pragma unroll
    for (int G = 0; G < 2; ++G)
#pragma unroll
        for (int j = 0; j < 4; ++j)
            cst[G][j] = z[(size_t)(row0 + G * 16 + 4 * kb + j) * 256 + 128 + cell * 32 + u];

    {   // h-init -> parity-1: 4 cells x 32 rows x 32 units / 512 thr = 8 each
        int ct = tid >> 7, rem = tid & 127, rr = rem >> 2, u8 = (rem & 3) * 8;
        const float* src = z + (size_t)(row0 + rr) * 256 + ct * 32 + u8;
#pragma unroll
        for (int e = 0; e < 8; ++e)
            Hsh[ct][rr >> 4][1][rr & 15][u8 + e] = rne_bf16(src[e]);
    }
    __syncthreads();

    f4v accp[4];
    // h-part precompute for the wave's NEXT work item (wave-private h);
    // bias enters here as the C-operand.
    auto hpart = [&](int G, int rpar) {
        bf8v hh = *(const bf8v*)&Hsh[cell][G][rpar][a][kb * 8];
        __builtin_amdgcn_s_setprio(1);
#pragma unroll
        for (int g = 0; g < 4; ++g) accp[g] = mfma_bf16(hh, WH[g][2], bC[g]);
        __builtin_amdgcn_s_setprio(0);
    };
    // post-barrier finish: V-read -> 8 MFMA -> lstm -> writes. par == t&1.
    auto finish = [&](int G, int t, int par, bool isA, bool hasV) {
        if (hasV) {
            const unsigned short (*Vh)[72] = isA ? Ysh[G][par ^ 1] : Msh[G];
            bf8v vh0 = *(const bf8v*)&Vh[a][kb * 8];
            bf8v vh1 = *(const bf8v*)&Vh[a][32 + kb * 8];
            __builtin_amdgcn_s_setprio(1);
#pragma unroll
            for (int g = 0; g < 4; ++g) {
                accp[g] = mfma_bf16(vh0, WH[g][0], accp[g]);
                accp[g] = mfma_bf16(vh1, WH[g][1], accp[g]);
            }
            __builtin_amdgcn_s_setprio(0);
        }
#pragma unroll
        for (int j = 0; j < 4; ++j) {
            float hv = lstm_one(accp[0][j], accp[1][j], accp[2][j], accp[3][j], cst[G][j]);
            unsigned short hp = rne_bf16(hv);
            int r = 4 * kb + j;
            Hsh[cell][G][par][r][u] = hp;
            if (isA) {
                Msh[G][r][cl * 32 + u] = hp;
            } else {
                Ysh[G][par][r][cl * 32 + u] = hp;
                xhat[((size_t)(row0 + G * 16 + r) * Tn + t) * Fn + cl * 32 + u] = hv;
            }
        }
    };

    hpart(0, 1);   // prologue: both A and B start on (G0, t=0)
    for (int it = 0; it < Tn / 2; ++it) {
        const int t0 = 2 * it, t1 = t0 + 1;
        const bool nz = (it > 0);
        PINW(WH);
        // ---- t0 (par 0) ---- slot even: A(G0,t0), B(G1,t0-1)
        if (P == 0) { finish(0, t0, 0, true, nz);            hpart(1, 1); }
        else        { if (nz) finish(1, t0 - 1, 1, false, true); hpart(0, 1); }
        lds_barrier_relaxed();
        //                      slot odd: A(G1,t0), B(G0,t0)
        if (P == 0) { finish(1, t0, 0, true, nz);            hpart(0, 0); }
        else        { finish(0, t0, 0, false, true);         hpart(1, 1); }
        lds_barrier_relaxed();
        PINW(WH);
        // ---- t1 (par 1) ---- slot even: A(G0,t1), B(G1,t0)
        if (P == 0) { finish(0, t1, 1, true, true);          hpart(1, 0); }
        else        { finish(1, t0, 0, false, true);         hpart(0, 0); }
        lds_barrier_relaxed();
        //                      slot odd: A(G1,t1), B(G0,t1)
        if (P == 0) { finish(1, t1, 1, true, true);          hpart(0, 1); }
        else        { finish(0, t1, 1, false, true);         hpart(1, 0); }
        lds_barrier_relaxed();
    }
    if (P == 1) finish(1, Tn - 1, 1, false, true);   // epilogue: G1 last step
}

extern "C" void kernel_launch(void* const* d_in, const int* in_sizes, int n_in,
                              void* d_out, int out_size, void* d_ws, size_t ws_size,
                              hipStream_t stream) {
    const float* x    = (const float*)d_in[0];
    const float* h0   = (const float*)d_in[1];
    const float* c0   = (const float*)d_in[2];
    const float* eWih = (const float*)d_in[3];
    const float* eWhh = (const float*)d_in[4];
    const float* eb   = (const float*)d_in[5];
    const float* dWih = (const float*)d_in[6];
    const float* dWhh = (const float*)d_in[7];
    const float* db   = (const float*)d_in[8];

    float* out = (float*)d_out;
    unsigned short* xs1h = (unsigned short*)d_out;          // [T,B,64] bf16 plane
    float* zb = out + (size_t)XHAT_ELEMS;                   // [B,256] latent
    unsigned short* wsb = (unsigned short*)d_ws;            // weight fragments

    hipLaunchKernelGGL(prep_kernel, dim3(48), dim3(256), 0, stream,
                       eWih, eWhh, dWih, dWhh, wsb);
    // encoder layer 0: x -> xs1 plane + z slots 0,1
    hipLaunchKernelGGL((enc_kernel<1>), dim3(Bn / 16), dim3(256), 0, stream,
                       x, (const unsigned short*)nullptr,
                       h0, c0, wsb, eb, 0, xs1h, zb);
    // encoder layer 1: xs1 plane -> z slots 2,3
    hipLaunchKernelGGL((enc_kernel<0>), dim3(Bn / 16), dim3(256), 0, stream,
                       (const float*)nullptr, xs1h,
                       h0, c0, wsb, eb, 1, (unsigned short*)nullptr, zb);
    // decoder: z -> x_hat (overwrites xs1 region)
    hipLaunchKernelGGL(dec_kernel, dim3(Bn / 32), dim3(512), 0, stream,
                       wsb + 98304, db, zb, out);
}

// Round 12
// 260.340 us; speedup vs baseline: 1.0548x; 1.0169x over previous
//
#include <hip/hip_runtime.h>
#include <cstddef>
#include <cstdint>

#define Tn 52
#define Fn 64
#define Hn 32
#define Bn 8192
#define XHAT_ELEMS (Bn * Tn * Fn)   // fp32 elems of x_hat; xs1 bf16 plane fits in half
#define L2E 1.44269504088896340736f

typedef __attribute__((ext_vector_type(8))) short bf8v;   // 8 bf16 (4 VGPRs)
typedef __attribute__((ext_vector_type(4))) float f4v;    // 4 fp32 accum
typedef __attribute__((ext_vector_type(2))) float f2v;    // packed-f32 pair

__device__ __forceinline__ f4v mfma_bf16(bf8v a, bf8v b, f4v c) {
    return __builtin_amdgcn_mfma_f32_16x16x32_bf16(a, b, c, 0, 0, 0);
}

// RNE round to bf16
__device__ __forceinline__ unsigned short rne_bf16(float v) {
    unsigned b = __float_as_uint(v);
    unsigned r = ((b >> 16) & 1u) + 0x7FFFu;
    return (unsigned short)((b + r) >> 16);
}

__device__ __forceinline__ bf8v rne8(float4 a, float4 b) {
    float v[8] = {a.x, a.y, a.z, a.w, b.x, b.y, b.z, b.w};
    bf8v r;
#pragma unroll
    for (int j = 0; j < 8; ++j) r[j] = (short)rne_bf16(v[j]);
    return r;
}

// encoder barrier (best-measured R7 flavor): sched pins
__device__ __forceinline__ void lds_barrier_pinned() {
    __builtin_amdgcn_sched_barrier(0);
    asm volatile("s_waitcnt lgkmcnt(0)" ::: "memory");
    __builtin_amdgcn_s_barrier();
    __builtin_amdgcn_sched_barrier(0);
}

// decoder barrier (best-measured R8 flavor): relaxed
__device__ __forceinline__ void lds_barrier_relaxed() {
    asm volatile("s_waitcnt lgkmcnt(0)" ::: "memory");
    __builtin_amdgcn_s_barrier();
}

// exp2(min(40, -a)) elementwise on a pair (trans ops are scalar; clamp scalar)
__device__ __forceinline__ f2v nexp2c(f2v a) {
    f2v r;
    r.x = exp2f(fminf(40.f, -a.x));
    r.y = exp2f(fminf(40.f, -a.y));
    return r;
}
__device__ __forceinline__ f2v rcp2(f2v a) {
    f2v r;
    r.x = __builtin_amdgcn_rcpf(a.x);
    r.y = __builtin_amdgcn_rcpf(a.y);
    return r;
}

// Packed-f32 LSTM update on a pair of units. Gates pre-scaled by log2e
// (g-gate by 2*log2e). Same per-element operation sequence as the scalar
// version -> bitwise-identical results; arithmetic emits v_pk_* ops.
__device__ __forceinline__ f2v lstm_pair(f2v aI, f2v aF, f2v aG, f2v aO, f2v& cst) {
    const f2v one = {1.f, 1.f};
    f2v ei = nexp2c(aI);
    f2v ef = nexp2c(aF);
    f2v eg = nexp2c(aG);
    f2v eo = nexp2c(aO);
    f2v p   = (one + ei) * (one + eg);
    f2v num = cst * p + (one - eg) * (one + ef);
    f2v den = (one + ef) * p;
    f2v c2  = num * rcp2(den);
    cst = c2;
    f2v t2 = c2 * (f2v){2.f * L2E, 2.f * L2E};   // e2 = exp2(min(40, -t2))
    f2v e2 = nexp2c(t2);
    return (one - e2) * rcp2((one + eo) * (one + e2));
}

// pin the 12 weight fragments live across the loop (defeats remat/reload)
#define PINW(W)                                                               \
    asm volatile("" : "+v"(W[0][0]), "+v"(W[0][1]), "+v"(W[0][2]),            \
                      "+v"(W[1][0]), "+v"(W[1][1]), "+v"(W[1][2]));           \
    asm volatile("" : "+v"(W[2][0]), "+v"(W[2][1]), "+v"(W[2][2]),            \
                      "+v"(W[3][0]), "+v"(W[3][1]), "+v"(W[3][2]));

// ---------------------------------------------------------------------------
// Prep: weights -> fragment-ordered RNE bf16, pre-scaled by log2e
// (g-gate rows by 2*log2e). [grp][cell(4)][nt(8)][ki(3)][lane(64)][j(8)]
//   gate = nt*16 + (lane&15); k = ki*32 + (lane>>4)*8 + j
// ---------------------------------------------------------------------------
__global__ void prep_kernel(const float* __restrict__ eWih, const float* __restrict__ eWhh,
                            const float* __restrict__ dWih, const float* __restrict__ dWhh,
                            unsigned short* __restrict__ ws)
{
    int fid = blockIdx.x * 256 + threadIdx.x;
    if (fid >= 12288) return;
    int lane = fid & 63;
    int ki   = (fid >> 6) % 3;
    int nt   = (fid / 192) & 7;
    int cell = (fid / 1536) & 3;
    int grp  = fid / 6144;
    const float* Wih = grp ? dWih : eWih;
    const float* Whh = grp ? dWhh : eWhh;
    int gate = nt * 16 + (lane & 15);
    float scale = ((gate >> 5) == 2) ? 2.f * L2E : L2E;
    int k0 = ki * 32 + (lane >> 4) * 8;
    size_t base = (size_t)grp * 98304 + (size_t)cell * 12288 + nt * 1536 + ki * 512 + lane * 8;
#pragma unroll
    for (int j = 0; j < 8; ++j) {
        int k = k0 + j;
        float v = (k < 64) ? Wih[(size_t)cell * 8192 + gate * 64 + k]
                           : Whh[(size_t)cell * 4096 + gate * 32 + (k - 64)];
        ws[base + j] = rne_bf16(v * scale);
    }
}

// ---------------------------------------------------------------------------
// Encoder layer (R7 structure, best-measured): block = 256 thr (4 waves =
// dir x q-half), 16 rows, grid 512. x-part MFMAs of t+1 hoisted pre-barrier.
// ---------------------------------------------------------------------------
template<int IS_L0>
__global__ __launch_bounds__(256, 2)
void enc_kernel(const float* __restrict__ X, const unsigned short* __restrict__ Xh,
                const float* __restrict__ h0, const float* __restrict__ c0,
                const unsigned short* __restrict__ Whi, const float* __restrict__ bias,
                int layer, unsigned short* __restrict__ outh, float* __restrict__ z)
{
    __shared__ __align__(16) unsigned short Hsh[2][2][16][40];   // [dir][parity][row][unit]
    const int tid = threadIdx.x, w = tid >> 6, lane = tid & 63;
    const int d = w >> 1, q = w & 1;
    const int a = lane & 15, kb = lane >> 4;
    const int u = q * 16 + a;
    const int row0 = blockIdx.x * 16;
    const int ci = 2 * layer + d;

    bf8v WH[4][3];   // 12 frags = 48 VGPR, pinned
#pragma unroll
    for (int g = 0; g < 4; ++g)
#pragma unroll
        for (int ki = 0; ki < 3; ++ki)
            WH[g][ki] = *(const bf8v*)(Whi + (size_t)ci * 12288 + (2 * g + q) * 1536
                                       + ki * 512 + lane * 8);
    float bj[4];
#pragma unroll
    for (int g = 0; g < 4; ++g)
        bj[g] = bias[ci * 128 + g * 32 + u] * ((g == 2) ? 2.f * L2E : L2E);
    float cst[4], hfin[4];
#pragma unroll
    for (int j = 0; j < 4; ++j)
        cst[j] = c0[((size_t)ci * Bn + row0 + 4 * kb + j) * Hn + u];

    {   // h0 -> parity 1: 2 dirs x 16 rows x 32 units / 256 thr = 4 each
        int dd = tid >> 7, rr = (tid >> 3) & 15, u4 = (tid & 7) * 4;
        const float* src = h0 + ((size_t)(2 * layer + dd) * Bn + row0 + rr) * Hn + u4;
#pragma unroll
        for (int e = 0; e < 4; ++e)
            Hsh[dd][1][rr][u4 + e] = rne_bf16(src[e]);
    }
    __syncthreads();

    const int grow = row0 + a;   // this lane's A-fragment row
    float4 p0, p1, p2, p3; bf8v ph0, ph1;
    f4v acc[4];
    {   // t = 0: load x, build acc = bias + x-part; prefetch t = 1
        int tt = d ? (Tn - 1) : 0;
        bf8v xf0, xf1;
        if (IS_L0) {
            const float* sp = X + ((size_t)grow * Tn + tt) * Fn;
            xf0 = rne8(*(const float4*)(sp + kb * 8), *(const float4*)(sp + kb * 8 + 4));
            xf1 = rne8(*(const float4*)(sp + 32 + kb * 8), *(const float4*)(sp + 32 + kb * 8 + 4));
        } else {
            size_t so = ((size_t)tt * Bn + grow) * Fn + kb * 8;
            xf0 = *(const bf8v*)(Xh + so);
            xf1 = *(const bf8v*)(Xh + so + 32);
        }
#pragma unroll
        for (int g = 0; g < 4; ++g) {
            acc[g] = (f4v){bj[g], bj[g], bj[g], bj[g]};
            acc[g] = mfma_bf16(xf0, WH[g][0], acc[g]);
            acc[g] = mfma_bf16(xf1, WH[g][1], acc[g]);
        }
        int tt1 = d ? (Tn - 2) : 1;
        if (IS_L0) {
            const float* sp = X + ((size_t)grow * Tn + tt1) * Fn;
            p0 = *(const float4*)(sp + kb * 8);      p1 = *(const float4*)(sp + kb * 8 + 4);
            p2 = *(const float4*)(sp + 32 + kb * 8); p3 = *(const float4*)(sp + 32 + kb * 8 + 4);
        } else {
            size_t so = ((size_t)tt1 * Bn + grow) * Fn + kb * 8;
            ph0 = *(const bf8v*)(Xh + so);
            ph1 = *(const bf8v*)(Xh + so + 32);
        }
    }

    for (int t = 0; t < Tn; ++t) {
        PINW(WH);
        // post-barrier critical path: h-read -> 4 MFMA -> lstm -> write
        bf8v hh = *(const bf8v*)&Hsh[d][(t & 1) ^ 1][a][kb * 8];
#pragma unroll
        for (int g = 0; g < 4; ++g) acc[g] = mfma_bf16(hh, WH[g][2], acc[g]);
        int tp = d ? (Tn - 1 - t) : t;
#pragma unroll
        for (int jp = 0; jp < 2; ++jp) {
            f2v aI = {acc[0][2 * jp], acc[0][2 * jp + 1]};
            f2v aF = {acc[1][2 * jp], acc[1][2 * jp + 1]};
            f2v aG = {acc[2][2 * jp], acc[2][2 * jp + 1]};
            f2v aO = {acc[3][2 * jp], acc[3][2 * jp + 1]};
            f2v cc = {cst[2 * jp], cst[2 * jp + 1]};
            f2v hv = lstm_pair(aI, aF, aG, aO, cc);
            cst[2 * jp] = cc.x;  cst[2 * jp + 1] = cc.y;
            hfin[2 * jp] = hv.x; hfin[2 * jp + 1] = hv.y;
            unsigned short hp0 = rne_bf16(hv.x), hp1 = rne_bf16(hv.y);
            Hsh[d][t & 1][4 * kb + 2 * jp][u]     = hp0;
            Hsh[d][t & 1][4 * kb + 2 * jp + 1][u] = hp1;
            if (IS_L0) {
                outh[((size_t)tp * Bn + row0 + 4 * kb + 2 * jp) * Fn + d * 32 + u]     = hp0;
                outh[((size_t)tp * Bn + row0 + 4 * kb + 2 * jp + 1) * Fn + d * 32 + u] = hp1;
            }
        }
        // pre-barrier: x-part of t+1 + prefetch t+2 (independent of h)
        {
            bf8v xf0, xf1;
            if (IS_L0) { xf0 = rne8(p0, p1); xf1 = rne8(p2, p3); }
            else       { xf0 = ph0; xf1 = ph1; }
#pragma unroll
            for (int g = 0; g < 4; ++g) {
                f4v t0 = (f4v){bj[g], bj[g], bj[g], bj[g]};
                t0 = mfma_bf16(xf0, WH[g][0], t0);
                acc[g] = mfma_bf16(xf1, WH[g][1], t0);
            }
            int ts = (t + 2 < Tn) ? t + 2 : Tn - 1;
            int tt = d ? (Tn - 1 - ts) : ts;
            if (IS_L0) {
                const float* sp = X + ((size_t)grow * Tn + tt) * Fn;
                p0 = *(const float4*)(sp + kb * 8);      p1 = *(const float4*)(sp + kb * 8 + 4);
                p2 = *(const float4*)(sp + 32 + kb * 8); p3 = *(const float4*)(sp + 32 + kb * 8 + 4);
            } else {
                size_t so = ((size_t)tt * Bn + grow) * Fn + kb * 8;
                ph0 = *(const bf8v*)(Xh + so);
                ph1 = *(const bf8v*)(Xh + so + 32);
            }
        }
        lds_barrier_pinned();
    }
#pragma unroll
    for (int j = 0; j < 4; ++j) {
        size_t zr = (size_t)(row0 + 4 * kb + j) * 256;
        z[zr + ci * 32 + u]       = hfin[j];
        z[zr + 128 + ci * 32 + u] = cst[j];
    }
}

// ---------------------------------------------------------------------------
// Decoder (R8 structure, best-measured): block = 512 thr (8 waves: P x cell x
// q-half), 32 rows = 2 groups, grid 256. Slot pipeline A/B on alternating
// groups; h-part of next slot hoisted pre-barrier; x2 unroll; setprio.
// ---------------------------------------------------------------------------
__global__ __launch_bounds__(512, 2)
void dec_kernel(const unsigned short* __restrict__ Whi, const float* __restrict__ bias,
                const float* __restrict__ z, float* __restrict__ xhat)
{
    __shared__ __align__(16) unsigned short Ysh[2][2][16][72];      // [grp][par][row][feat]
    __shared__ __align__(16) unsigned short Msh[2][16][72];         // [grp][row][feat]
    __shared__ __align__(16) unsigned short Hsh[4][2][2][16][40];   // [cell][grp][par][row][unit]

    const int tid = threadIdx.x, w = tid >> 6, lane = tid & 63;
    const int P = w >> 2, cl = (w >> 1) & 1, q = w & 1;
    const int cell = P * 2 + cl;
    const int a = lane & 15, kb = lane >> 4, u = q * 16 + a;
    const int row0 = blockIdx.x * 32;

    bf8v WH[4][3];   // 12 frags = 48 VGPR, pinned
#pragma unroll
    for (int g = 0; g < 4; ++g)
#pragma unroll
        for (int ki = 0; ki < 3; ++ki)
            WH[g][ki] = *(const bf8v*)(Whi + (size_t)cell * 12288 + (2 * g + q) * 1536
                                       + ki * 512 + lane * 8);
    f4v bC[4];
#pragma unroll
    for (int g = 0; g < 4; ++g) {
        float bv = bias[cell * 128 + g * 32 + u] * ((g == 2) ? 2.f * L2E : L2E);
        bC[g] = (f4v){bv, bv, bv, bv};
    }

    float cst[2][4];   // [group][j]
#pragma unroll
    for (int G = 0; G < 2; ++G)
#pragma unroll
        for (int j = 0; j < 4; ++j)
            cst[G][j] = z[(size_t)(row0 + G * 16 + 4 * kb + j) * 256 + 128 + cell * 32 + u];

    {   // h-init -> parity-1: 4 cells x 32 rows x 32 units / 512 thr = 8 each
        int ct = tid >> 7, rem = tid & 127, rr = rem >> 2, u8 = (rem & 3) * 8;
        const float* src = z + (size_t)(row0 + rr) * 256 + ct * 32 + u8;
#pragma unroll
        for (int e = 0; e < 8; ++e)
            Hsh[ct][rr >> 4][1][rr & 15][u8 + e] = rne_bf16(src[e]);
    }
    __syncthreads();

    f4v accp[4];
    // h-part precompute for the wave's NEXT work item (wave-private h);
    // bias enters here as the C-operand.
    auto hpart = [&](int G, int rpar) {
        bf8v hh = *(const bf8v*)&Hsh[cell][G][rpar][a][kb * 8];
        __builtin_amdgcn_s_setprio(1);
#pragma unroll
        for (int g = 0; g < 4; ++g) accp[g] = mfma_bf16(hh, WH[g][2], bC[g]);
        __builtin_amdgcn_s_setprio(0);
    };
    // post-barrier finish: V-read -> 8 MFMA -> lstm -> writes. par == t&1.
    auto finish = [&](int G, int t, int par, bool isA, bool hasV) {
        if (hasV) {
            const unsigned short (*Vh)[72] = isA ? Ysh[G][par ^ 1] : Msh[G];
            bf8v vh0 = *(const bf8v*)&Vh[a][kb * 8];
            bf8v vh1 = *(const bf8v*)&Vh[a][32 + kb * 8];
            __builtin_amdgcn_s_setprio(1);
#pragma unroll
            for (int g = 0; g < 4; ++g) {
                accp[g] = mfma_bf16(vh0, WH[g][0], accp[g]);
                accp[g] = mfma_bf16(vh1, WH[g][1], accp[g]);
            }
            __builtin_amdgcn_s_setprio(0);
        }
#pragma unroll
        for (int jp = 0; jp < 2; ++jp) {
            f2v aI = {accp[0][2 * jp], accp[0][2 * jp + 1]};
            f2v aF = {accp[1][2 * jp], accp[1][2 * jp + 1]};
            f2v aG = {accp[2][2 * jp], accp[2][2 * jp + 1]};
            f2v aO = {accp[3][2 * jp], accp[3][2 * jp + 1]};
            f2v cc = {cst[G][2 * jp], cst[G][2 * jp + 1]};
            f2v hv = lstm_pair(aI, aF, aG, aO, cc);
            cst[G][2 * jp] = cc.x;  cst[G][2 * jp + 1] = cc.y;
            unsigned short hp0 = rne_bf16(hv.x), hp1 = rne_bf16(hv.y);
            int r0 = 4 * kb + 2 * jp, r1 = r0 + 1;
            Hsh[cell][G][par][r0][u] = hp0;
            Hsh[cell][G][par][r1][u] = hp1;
            if (isA) {
                Msh[G][r0][cl * 32 + u] = hp0;
                Msh[G][r1][cl * 32 + u] = hp1;
            } else {
                Ysh[G][par][r0][cl * 32 + u] = hp0;
                Ysh[G][par][r1][cl * 32 + u] = hp1;
                xhat[((size_t)(row0 + G * 16 + r0) * Tn + t) * Fn + cl * 32 + u] = hv.x;
                xhat[((size_t)(row0 + G * 16 + r1) * Tn + t) * Fn + cl * 32 + u] = hv.y;
            }
        }
    };

    hpart(0, 1);   // prologue: both A and B start on (G0, t=0)
    for (int it = 0; it < Tn / 2; ++it) {
        const int t0 = 2 * it, t1 = t0 + 1;
        const bool nz = (it > 0);
        PINW(WH);
        // ---- t0 (par 0) ---- slot even: A(G0,t0), B(G1,t0-1)
        if (P == 0) { finish(0, t0, 0, true, nz);            hpart(1, 1); }
        else        { if (nz) finish(1, t0 - 1, 1, false, true); hpart(0, 1); }
        lds_barrier_relaxed();
        //                      slot odd: A(G1,t0), B(G0,t0)
        if (P == 0) { finish(1, t0, 0, true, nz);            hpart(0, 0); }
        else        { finish(0, t0, 0, false, true);         hpart(1, 1); }
        lds_barrier_relaxed();
        PINW(WH);
        // ---- t1 (par 1) ---- slot even: A(G0,t1), B(G1,t0)
        if (P == 0) { finish(0, t1, 1, true, true);          hpart(1, 0); }
        else        { finish(1, t0, 0, false, true);         hpart(0, 0); }
        lds_barrier_relaxed();
        //                      slot odd: A(G1,t1), B(G0,t1)
        if (P == 0) { finish(1, t1, 1, true, true);          hpart(0, 1); }
        else        { finish(0, t1, 1, false, true);         hpart(1, 0); }
        lds_barrier_relaxed();
    }
    if (P == 1) finish(1, Tn - 1, 1, false, true);   // epilogue: G1 last step
}

extern "C" void kernel_launch(void* const* d_in, const int* in_sizes, int n_in,
                              void* d_out, int out_size, void* d_ws, size_t ws_size,
                              hipStream_t stream) {
    const float* x    = (const float*)d_in[0];
    const float* h0   = (const float*)d_in[1];
    const float* c0   = (const float*)d_in[2];
    const float* eWih = (const float*)d_in[3];
    const float* eWhh = (const float*)d_in[4];
    const float* eb   = (const float*)d_in[5];
    const float* dWih = (const float*)d_in[6];
    const float* dWhh = (const float*)d_in[7];
    const float* db   = (const float*)d_in[8];

    float* out = (float*)d_out;
    unsigned short* xs1h = (unsigned short*)d_out;          // [T,B,64] bf16 plane
    float* zb = out + (size_t)XHAT_ELEMS;                   // [B,256] latent
    unsigned short* wsb = (unsigned short*)d_ws;            // weight fragments

    hipLaunchKernelGGL(prep_kernel, dim3(48), dim3(256), 0, stream,
                       eWih, eWhh, dWih, dWhh, wsb);
    // encoder layer 0: x -> xs1 plane + z slots 0,1
    hipLaunchKernelGGL((enc_kernel<1>), dim3(Bn / 16), dim3(256), 0, stream,
                       x, (const unsigned short*)nullptr,
                       h0, c0, wsb, eb, 0, xs1h, zb);
    // encoder layer 1: xs1 plane -> z slots 2,3
    hipLaunchKernelGGL((enc_kernel<0>), dim3(Bn / 16), dim3(256), 0, stream,
                       (const float*)nullptr, xs1h,
                       h0, c0, wsb, eb, 1, (unsigned short*)nullptr, zb);
    // decoder: z -> x_hat (overwrites xs1 region)
    hipLaunchKernelGGL(dec_kernel, dim3(Bn / 32), dim3(512), 0, stream,
                       wsb + 98304, db, zb, out);
}